// Round 16
// baseline (801.459 us; speedup 1.0000x reference)
//
#include <hip/hip_runtime.h>

// DGraphDTA r16: r15 with node-GEMM BK 16->32 (barriers/block halved at
// CONSTANT occupancy: LDS 8.7->16.9KB still allows 9 blocks/CU > 8-block
// thread cap; no prefetch registers, unlike r14). Everything else = r15.

static inline int cdiv(int a, int b) { return (a + b - 1) / b; }

// ---------------- fused CSR build ----------------

__global__ void deg2_kernel(const int* __restrict__ dstA, int* __restrict__ degA, int EA,
                            const int* __restrict__ dstB, int* __restrict__ degB, int EB) {
    int t = blockIdx.x * blockDim.x + threadIdx.x;
    if (t < EA) { atomicAdd(&degA[dstA[t]], 1); return; }
    t -= EA;
    if (t < EB) atomicAdd(&degB[dstB[t]], 1);
}

__global__ void degsum2_kernel(const int* __restrict__ deg_p, int NP, int nbp,
                               const int* __restrict__ deg_m, int NM, int* __restrict__ bsum) {
    __shared__ int s[256];
    int b = blockIdx.x, tid = threadIdx.x;
    const int* deg; int N, bi;
    if (b < nbp) { deg = deg_p; N = NP; bi = b; }
    else         { deg = deg_m; N = NM; bi = b - nbp; }
    int t = bi * 256 + tid;
    s[tid] = (t < N) ? deg[t] : 0;
    __syncthreads();
    for (int off = 128; off > 0; off >>= 1) {
        if (tid < off) s[tid] += s[tid + off];
        __syncthreads();
    }
    if (tid == 0) bsum[b] = s[0];
}

__global__ void scan2_kernel(int* __restrict__ bsum, int nbp, int nbm) {
    __shared__ int s[512];
    int tid = threadIdx.x;
    int total = nbp + nbm;
    int v = (tid < total) ? bsum[tid] : 0;
    bool isMol = (tid >= nbp);
    s[tid] = v;
    __syncthreads();
    for (int off = 1; off < 512; off <<= 1) {
        int x = 0;
        if (tid >= off) {
            int src = tid - off;
            if ((src >= nbp) == isMol) x = s[src];
        }
        __syncthreads();
        s[tid] += x;
        __syncthreads();
    }
    if (tid < total) bsum[tid] = s[tid] - v;
}

__global__ void alloc_scan2_kernel(const int* __restrict__ deg_p, int* rs_p, int* fc_p, float* n_p,
                                   int NP, int nbp,
                                   const int* __restrict__ deg_m, int* rs_m, int* fc_m, float* n_m,
                                   int NM, const int* __restrict__ bsum) {
    __shared__ int s[256];
    int b = blockIdx.x, tid = threadIdx.x;
    const int* deg; int* rs; int* fc; float* nrm; int N, bi;
    if (b < nbp) { deg = deg_p; rs = rs_p; fc = fc_p; nrm = n_p; N = NP; bi = b; }
    else         { deg = deg_m; rs = rs_m; fc = fc_m; nrm = n_m; N = NM; bi = b - nbp; }
    int t = bi * 256 + tid;
    int v = (t < N) ? deg[t] : 0;
    s[tid] = v;
    __syncthreads();
    for (int off = 1; off < 256; off <<= 1) {
        int x = (tid >= off) ? s[tid - off] : 0;
        __syncthreads();
        s[tid] += x;
        __syncthreads();
    }
    if (t < N) {
        int start = bsum[b] + s[tid] - v;
        rs[t] = start;
        fc[t] = start;
        nrm[t] = rsqrtf((float)v + 1.0f);
    }
}

__global__ void fill2_kernel(const int* srcA, const int* dstA, int* fcA, int* esA, int EA,
                             const int* srcB, const int* dstB, int* fcB, int* esB, int EB) {
    int t = blockIdx.x * blockDim.x + threadIdx.x;
    if (t < EA) { int p = atomicAdd(&fcA[dstA[t]], 1); esA[p] = srcA[t]; return; }
    t -= EA;
    if (t < EB) { int p = atomicAdd(&fcB[dstB[t]], 1); esB[p] = srcB[t]; }
}

__device__ __forceinline__ void gs_body(const int* batch, int* gs, int t, int N, int B) {
    int b = batch[t];
    int bp = (t == 0) ? -1 : batch[t - 1];
    for (int g = bp + 1; g <= b; ++g) gs[g] = t;
    if (t == N - 1) for (int g = b + 1; g <= B; ++g) gs[g] = N;
}

__global__ void gs2_kernel(const int* batchA, int* gsA, int NA,
                           const int* batchB, int* gsB, int NB, int B) {
    int t = blockIdx.x * blockDim.x + threadIdx.x;
    if (t < NA) { gs_body(batchA, gsA, t, NA, B); return; }
    t -= NA;
    if (t < NB) gs_body(batchB, gsB, t, NB, B);
}

__global__ void pad2_kernel(const float* xA, float* yA, int NA, int FA, int SA,
                            const float* xB, float* yB, int NB, int FB, int SB) {
    int t = blockIdx.x * blockDim.x + threadIdx.x;
    if (t < NA * SA) {
        int r = t / SA, j = t - r * SA;
        yA[t] = (j < FA) ? xA[(size_t)r * FA + j] : 0.0f;
        return;
    }
    t -= NA * SA;
    if (t < NB * SB) {
        int r = t / SB, j = t - r * SB;
        yB[t] = (j < FB) ? xB[(size_t)r * FB + j] : 0.0f;
    }
}

// ---------------- fused float4 gather-aggregate (norm fused, unroll x4) ----------------

__device__ __forceinline__ float4 vmad(float s, float4 a, float4 b) {
    return make_float4(fmaf(s, a.x, b.x), fmaf(s, a.y, b.y), fmaf(s, a.z, b.z), fmaf(s, a.w, b.w));
}
__device__ __forceinline__ float4 vmul(float s, float4 a) {
    return make_float4(s * a.x, s * a.y, s * a.z, s * a.w);
}
__device__ __forceinline__ float4 vadd(float4 a, float4 b) {
    return make_float4(a.x + b.x, a.y + b.y, a.z + b.z, a.w + b.w);
}

__device__ __forceinline__ void gather_body(
    const float* __restrict__ x, const float* __restrict__ norm,
    const int* __restrict__ row_start, const int* __restrict__ deg,
    const int* __restrict__ edge_src, float* __restrict__ agg, int t, int Fv)
{
    int n = t / Fv;
    int jv = t - n * Fv;
    const float4* xv = reinterpret_cast<const float4*>(x);
    float4* aggv = reinterpret_cast<float4*>(agg);

    float4 acc = vmul(norm[n], xv[(size_t)n * Fv + jv]);
    float4 acc2 = make_float4(0.f, 0.f, 0.f, 0.f);
    int rs = row_start[n];
    int d = deg[n];
    const int* es = edge_src + rs;
    int i = 0;
    for (; i + 4 <= d; i += 4) {
        int s0 = es[i], s1 = es[i + 1], s2 = es[i + 2], s3 = es[i + 3];
        float n0 = norm[s0], n1 = norm[s1], n2 = norm[s2], n3 = norm[s3];
        float4 v0 = xv[(size_t)s0 * Fv + jv];
        float4 v1 = xv[(size_t)s1 * Fv + jv];
        float4 v2 = xv[(size_t)s2 * Fv + jv];
        float4 v3 = xv[(size_t)s3 * Fv + jv];
        acc  = vmad(n0, v0, acc);
        acc2 = vmad(n1, v1, acc2);
        acc  = vmad(n2, v2, acc);
        acc2 = vmad(n3, v3, acc2);
    }
    for (; i < d; ++i) {
        int s0 = es[i];
        acc = vmad(norm[s0], xv[(size_t)s0 * Fv + jv], acc);
    }
    aggv[t] = vadd(acc, acc2);
}

__global__ __launch_bounds__(256) void gather2_kernel(
    const float* xA, const float* nA, const int* rsA, const int* dA, const int* esA,
    float* aggA, int cntA, int FvA,
    const float* xB, const float* nB, const int* rsB, const int* dB, const int* esB,
    float* aggB, int cntB, int FvB)
{
    int t = blockIdx.x * blockDim.x + threadIdx.x;
    if (t < cntA) { gather_body(xA, nA, rsA, dA, esA, aggA, t, FvA); return; }
    t -= cntA;
    if (t < cntB) gather_body(xB, nB, rsB, dB, esB, aggB, t, FvB);
}

// ---------------- fused tiled GEMM (64x64/4x4, BK=32) ----------------

__device__ __forceinline__ void gemm_body(
    const float* __restrict__ X, const float* __restrict__ W,
    const float* __restrict__ bias, const float* __restrict__ scale,
    float* __restrict__ out, int M, int K, int N, int lda, int out_stride,
    int bx, int by, float* As, float* Bs)
{
    constexpr int BM = 64, BN = 64, BK = 32, LDA = BM + 4;
    const int tid = threadIdx.x;
    const int row0 = by * BM, col0 = bx * BN;
    const int tx = tid & 15, ty = tid >> 4;

    float acc[4][4] = {};

    const int a_lk = tid & 31;   // k within tile (0..31)
    const int a_r0 = tid >> 5;   // row base (8 passes, stride 8)
    const int b_lc = tid & 63;   // col
    const int b_lk = tid >> 6;   // 0..3 (8 passes, stride 4)

    for (int k0 = 0; k0 < K; k0 += BK) {
#pragma unroll
        for (int p = 0; p < 8; ++p) {
            int r = a_r0 + p * 8;
            int gm = row0 + r, gk = k0 + a_lk;
            As[a_lk * LDA + r] = (gm < M && gk < K) ? X[(size_t)gm * lda + gk] : 0.0f;
        }
#pragma unroll
        for (int p = 0; p < 8; ++p) {
            int kk = b_lk + p * 4;
            int gk = k0 + kk, gn = col0 + b_lc;
            Bs[kk * BN + b_lc] = (gk < K && gn < N) ? W[(size_t)gk * N + gn] : 0.0f;
        }
        __syncthreads();
#pragma unroll
        for (int k = 0; k < BK; ++k) {
            const float4 a4 = *reinterpret_cast<const float4*>(&As[k * LDA + ty * 4]);
            const float4 b4 = *reinterpret_cast<const float4*>(&Bs[k * BN + tx * 4]);
            const float av[4] = {a4.x, a4.y, a4.z, a4.w};
            const float bv[4] = {b4.x, b4.y, b4.z, b4.w};
#pragma unroll
            for (int i = 0; i < 4; ++i)
#pragma unroll
                for (int j = 0; j < 4; ++j)
                    acc[i][j] = fmaf(av[i], bv[j], acc[i][j]);
        }
        __syncthreads();
    }

#pragma unroll
    for (int i = 0; i < 4; ++i) {
        int gm = row0 + ty * 4 + i;
        if (gm >= M) continue;
        float sc = scale[gm];
#pragma unroll
        for (int j = 0; j < 4; ++j) {
            int gn = col0 + tx * 4 + j;
            if (gn >= N) continue;
            float v = sc * acc[i][j] + bias[gn];
            v = fmaxf(v, 0.0f);  // all node-layer gemms have relu
            out[(size_t)gm * out_stride + gn] = v;
        }
    }
}

__global__ __launch_bounds__(256) void gemm2_kernel(
    const float* XA, const float* WA, const float* biasA, const float* scaleA, float* outA,
    int MA, int KA, int NA, int ldaA, int osA, int nbA, int gxA,
    const float* XB, const float* WB, const float* biasB, const float* scaleB, float* outB,
    int MB, int KB, int NB, int ldaB, int osB, int gxB)
{
    __shared__ __align__(16) float As[32 * 68];
    __shared__ __align__(16) float Bs[32 * 64];
    int bid = blockIdx.x;
    if (bid < nbA) {
        gemm_body(XA, WA, biasA, scaleA, outA, MA, KA, NA, ldaA, osA, bid % gxA, bid / gxA, As, Bs);
    } else {
        bid -= nbA;
        gemm_body(XB, WB, biasB, scaleB, outB, MB, KB, NB, ldaB, osB, bid % gxB, bid / gxB, As, Bs);
    }
}

// ---------------- FC (M=256): M-reuse + deep split-K ----------------

template <bool RELU, int MR, int JT>
__device__ __forceinline__ void fc_body(
    const float* __restrict__ X, const float* __restrict__ W,
    const float* __restrict__ bias, float* __restrict__ out,
    int K, int N, int out_stride, int out_off, int bx, int by, float* smem)
{
    constexpr int TJ = JT / 4;
    constexpr int SK = 256 / TJ;
    float* Xs = smem;
    float* red = smem + MR * K;

    const int tid = threadIdx.x;
    const int m0 = by * MR;
    const int j0 = bx * JT;

    for (int idx = tid; idx < MR * K; idx += 256) {
        int r = idx / K, k = idx - r * K;
        Xs[idx] = X[(size_t)(m0 + r) * K + k];
    }
    __syncthreads();

    const int tj = tid % TJ;
    const int s  = tid / TJ;
    const int chunk = (K + SK - 1) / SK;
    const int kb = s * chunk;
    const int ke = min(K, kb + chunk);

    const float4* w4 = reinterpret_cast<const float4*>(W + j0) + tj;
    const int wstride = N >> 2;

    float4 acc[MR];
#pragma unroll
    for (int r = 0; r < MR; ++r) acc[r] = make_float4(0.f, 0.f, 0.f, 0.f);
    for (int k = kb; k < ke; ++k) {
        float4 w = w4[(size_t)k * wstride];
#pragma unroll
        for (int r = 0; r < MR; ++r)
            acc[r] = vmad(Xs[r * K + k], w, acc[r]);
    }
#pragma unroll
    for (int r = 0; r < MR; ++r) {
        float* rr = red + ((s * MR + r) * JT) + tj * 4;
        rr[0] = acc[r].x; rr[1] = acc[r].y; rr[2] = acc[r].z; rr[3] = acc[r].w;
    }
    __syncthreads();

    for (int o = tid; o < MR * JT; o += 256) {
        int r = o / JT, j = o - r * JT;
        float v = 0.f;
#pragma unroll
        for (int ss = 0; ss < SK; ++ss) v += red[(ss * MR + r) * JT + j];
        v += bias[j0 + j];
        if (RELU) v = fmaxf(v, 0.0f);
        out[(size_t)(m0 + r) * out_stride + out_off + j0 + j] = v;
    }
}

template <bool RELU, int MR, int JT>
__global__ __launch_bounds__(256) void fc2_kernel(
    const float* XA, const float* WA, const float* bA, float* oA,
    int KA, int NA, int osA, int ooA, int nbA, int gxA,
    const float* XB, const float* WB, const float* bB, float* oB,
    int KB, int NB, int osB, int ooB, int gxB)
{
    extern __shared__ float smem[];
    int bid = blockIdx.x;
    if (bid < nbA) {
        fc_body<RELU, MR, JT>(XA, WA, bA, oA, KA, NA, osA, ooA, bid % gxA, bid / gxA, smem);
    } else {
        bid -= nbA;
        fc_body<RELU, MR, JT>(XB, WB, bB, oB, KB, NB, osB, ooB, bid % gxB, bid / gxB, smem);
    }
}

template <bool RELU, int MR, int JT>
__global__ __launch_bounds__(256) void fc_kernel(
    const float* X, const float* W, const float* b, float* o,
    int K, int N, int out_stride, int out_off)
{
    extern __shared__ float smem[];
    fc_body<RELU, MR, JT>(X, W, b, o, K, N, out_stride, out_off, blockIdx.x, blockIdx.y, smem);
}

// final layer: one block per row, 256 threads, LDS tree reduce (K=512)
__global__ __launch_bounds__(256) void matvec_kernel(
    const float* __restrict__ X, const float* __restrict__ W,
    const float* __restrict__ bias, float* __restrict__ out, int K)
{
    __shared__ float red[256];
    const int m = blockIdx.x;
    const int tid = threadIdx.x;
    float acc = 0.f;
    for (int k = tid; k < K; k += 256) acc = fmaf(X[(size_t)m * K + k], W[k], acc);
    red[tid] = acc;
    __syncthreads();
    for (int w = 128; w >= 64; w >>= 1) {
        if (tid < w) red[tid] += red[tid + w];
        __syncthreads();
    }
    if (tid < 64) {
        float v = red[tid];
        for (int off = 32; off > 0; off >>= 1) v += __shfl_down(v, off, 64);
        if (tid == 0) out[m] = v + bias[0];
    }
}

// ---------------- fused pooling ----------------

__device__ __forceinline__ void pool_body(const float* __restrict__ x, const int* __restrict__ gs,
                                          float* __restrict__ pool, int t, int F, int stride) {
    int g = t / F;
    int j = t - g * F;
    int s = gs[g];
    int c = gs[g + 1] - s;
    float acc = 0.0f;
    for (int i = 0; i < c; ++i) acc += x[(size_t)(s + i) * stride + j];
    pool[t] = acc / (float)max(c, 1);
}

__global__ void pool2_kernel(const float* xA, const int* gsA, float* poolA, int cntA, int FA, int strA,
                             const float* xB, const int* gsB, float* poolB, int cntB, int FB, int strB) {
    int t = blockIdx.x * blockDim.x + threadIdx.x;
    if (t < cntA) { pool_body(xA, gsA, poolA, t, FA, strA); return; }
    t -= cntA;
    if (t < cntB) pool_body(xB, gsB, poolB, t, FB, strB);
}

extern "C" void kernel_launch(void* const* d_in, const int* in_sizes, int n_in,
                              void* d_out, int out_size, void* d_ws, size_t ws_size,
                              hipStream_t stream) {
    const float* mol_x     = (const float*)d_in[0];
    const int*   mol_ei    = (const int*)  d_in[1];
    const int*   mol_batch = (const int*)  d_in[2];
    const float* pro_x     = (const float*)d_in[3];
    const int*   pro_ei    = (const int*)  d_in[4];
    const int*   pro_batch = (const int*)  d_in[5];
    const float* mw1 = (const float*)d_in[6],  * mb1 = (const float*)d_in[7];
    const float* mw2 = (const float*)d_in[8],  * mb2 = (const float*)d_in[9];
    const float* mw3 = (const float*)d_in[10], * mb3 = (const float*)d_in[11];
    const float* mfw1 = (const float*)d_in[12], * mfb1 = (const float*)d_in[13];
    const float* mfw2 = (const float*)d_in[14], * mfb2 = (const float*)d_in[15];
    const float* pw1 = (const float*)d_in[16], * pb1 = (const float*)d_in[17];
    const float* pw2 = (const float*)d_in[18], * pb2 = (const float*)d_in[19];
    const float* pw3 = (const float*)d_in[20], * pb3 = (const float*)d_in[21];
    const float* pfw1 = (const float*)d_in[22], * pfb1 = (const float*)d_in[23];
    const float* pfw2 = (const float*)d_in[24], * pfb2 = (const float*)d_in[25];
    const float* fc1w = (const float*)d_in[26], * fc1b = (const float*)d_in[27];
    const float* fc2w = (const float*)d_in[28], * fc2b = (const float*)d_in[29];
    const float* outw = (const float*)d_in[30], * outb = (const float*)d_in[31];
    float* out = (float*)d_out;

    // ---- dims ----
    const int NP = 76800, EP = 768000;
    const int NM = 10240, EM = 40960;
    const int NBP = cdiv(NP, 256), NBM = cdiv(NM, 256);  // 300, 40

    // ---- workspace layout (floats then ints), ~167 MB ----
    float* Pp = (float*)d_ws;                  // 76800*216
    float* Qp = Pp + (size_t)NP * 216;         // 76800*108
    float* Rp = Qp + (size_t)NP * 108;         // 76800*108
    float* Pm = Rp + (size_t)NP * 108;         // 10240*312
    float* Qm = Pm + (size_t)NM * 312;         // 10240*156
    float* Rm = Qm + (size_t)NM * 156;         // 10240*156
    float* norm_p = Rm + (size_t)NM * 156;     // 76800
    float* norm_m = norm_p + NP;               // 10240
    float* pool_p = norm_m + NM;               // 256*216
    float* pool_m = pool_p + 256 * 216;        // 256*312
    float* fcb_p  = pool_m + 256 * 312;        // 256*1024
    float* fcb_m  = fcb_p + 256 * 1024;        // 256*1024
    float* xc     = fcb_m + 256 * 1024;        // 256*256
    float* hb1    = xc + 256 * 256;            // 256*1024
    float* hb2    = hb1 + 256 * 1024;          // 256*512
    int* ibase    = (int*)(hb2 + 256 * 512);
    int* deg_p = ibase;                        // 76800 (memset region start)
    int* deg_m = deg_p + NP;                   // 10240
    int* rs_p  = deg_m + NM;                   // 76800
    int* fc_p  = rs_p + NP;                    // 76800
    int* es_p  = fc_p + NP;                    // 768000
    int* rs_m  = es_p + EP;                    // 10240
    int* fc_m  = rs_m + NM;                    // 10240
    int* es_m  = fc_m + NM;                    // 40960
    int* gs_p  = es_m + EM;                    // 257 (+pad)
    int* gs_m  = gs_p + 260;                   // 257 (+pad)
    int* bsum  = gs_m + 260;                   // 384 (NBP+NBM=340)

    const int BLK = 256;

    // ---- fused CSR build (atomic-free allocation via block scans) ----
    hipMemsetAsync(deg_p, 0, (size_t)(NP + NM) * sizeof(int), stream);
    deg2_kernel<<<cdiv(EP + EM, BLK), BLK, 0, stream>>>(pro_ei + EP, deg_p, EP, mol_ei + EM, deg_m, EM);
    degsum2_kernel<<<NBP + NBM, 256, 0, stream>>>(deg_p, NP, NBP, deg_m, NM, bsum);
    scan2_kernel<<<1, 512, 0, stream>>>(bsum, NBP, NBM);
    alloc_scan2_kernel<<<NBP + NBM, 256, 0, stream>>>(deg_p, rs_p, fc_p, norm_p, NP, NBP,
                                                      deg_m, rs_m, fc_m, norm_m, NM, bsum);
    fill2_kernel<<<cdiv(EP + EM, BLK), BLK, 0, stream>>>(pro_ei, pro_ei + EP, fc_p, es_p, EP,
                                                         mol_ei, mol_ei + EM, fc_m, es_m, EM);
    gs2_kernel<<<cdiv(NP + NM, BLK), BLK, 0, stream>>>(pro_batch, gs_p, NP, mol_batch, gs_m, NM, 256);
    pad2_kernel<<<cdiv(NP * 56 + NM * 80, BLK), BLK, 0, stream>>>(pro_x, Rp, NP, 54, 56,
                                                                  mol_x, Rm, NM, 78, 80);

    // fused layer: gather both branches, then gemm both branches
    auto layer = [&](const float* xp, float* outp, const float* Wp, const float* bp,
                     int KpF, int Sp, int NpF, int SpO,
                     const float* xm, float* outm, const float* Wm, const float* bm,
                     int KmF, int Sm, int NmF, int SmO) {
        int cntP = NP * (Sp / 4), cntM = NM * (Sm / 4);
        gather2_kernel<<<cdiv(cntP + cntM, BLK), BLK, 0, stream>>>(
            xp, norm_p, rs_p, deg_p, es_p, Qp, cntP, Sp / 4,
            xm, norm_m, rs_m, deg_m, es_m, Qm, cntM, Sm / 4);
        int gxA = cdiv(NpF, 64), gyA = cdiv(NP, 64), nbA = gxA * gyA;
        int gxB = cdiv(NmF, 64), gyB = cdiv(NM, 64), nbB = gxB * gyB;
        gemm2_kernel<<<nbA + nbB, 256, 0, stream>>>(
            Qp, Wp, bp, norm_p, outp, NP, KpF, NpF, Sp, SpO, nbA, gxA,
            Qm, Wm, bm, norm_m, outm, NM, KmF, NmF, Sm, SmO, gxB);
    };

    // L1: R(padded x0) -> P ; L2: P -> R ; L3: R -> P
    layer(Rp, Pp, pw1, pb1, 54, 56, 54, 56,   Rm, Pm, mw1, mb1, 78, 80, 78, 80);
    layer(Pp, Rp, pw2, pb2, 54, 56, 108, 108, Pm, Rm, mw2, mb2, 78, 80, 156, 156);
    layer(Rp, Pp, pw3, pb3, 108, 108, 216, 216, Rm, Pm, mw3, mb3, 156, 156, 312, 312);

    // fused pool
    pool2_kernel<<<cdiv(256 * 216 + 256 * 312, BLK), BLK, 0, stream>>>(
        Pp, gs_p, pool_p, 256 * 216, 216, 216,
        Pm, gs_m, pool_m, 256 * 312, 312, 312);

    // fused branch fc1 (relu, K=216/312, N=1024): MR=4, JT=64; LDS sized for K=312
    {
        int gxA = 1024 / 64, nbA = gxA * (256 / 4);
        int gxB = 1024 / 64, nbB = gxB * (256 / 4);
        size_t lds = (size_t)(4 * 312 + 16 * 4 * 64) * sizeof(float);
        fc2_kernel<true, 4, 64><<<nbA + nbB, 256, lds, stream>>>(
            pool_p, pfw1, pfb1, fcb_p, 216, 1024, 1024, 0, nbA, gxA,
            pool_m, mfw1, mfb1, fcb_m, 312, 1024, 1024, 0, gxB);
    }
    // fused branch fc2 (no relu, K=1024, N=128 -> xc cols): MR=2, JT=32
    {
        int gxA = 128 / 32, nbA = gxA * (256 / 2);
        int gxB = gxA, nbB = nbA;
        size_t lds = (size_t)(2 * 1024 + 32 * 2 * 32) * sizeof(float);
        fc2_kernel<false, 2, 32><<<nbA + nbB, 256, lds, stream>>>(
            fcb_p, pfw2, pfb2, xc, 1024, 128, 256, 128, nbA, gxA,
            fcb_m, mfw2, mfb2, xc, 1024, 128, 256, 0, gxB);
    }

    // combined head
    {
        dim3 grid(1024 / 64, 256 / 4);
        size_t lds = (size_t)(4 * 256 + 16 * 4 * 64) * sizeof(float);
        fc_kernel<true, 4, 64><<<grid, 256, lds, stream>>>(xc, fc1w, fc1b, hb1, 256, 1024, 1024, 0);
    }
    {
        dim3 grid(512 / 64, 256 / 4);
        size_t lds = (size_t)(4 * 1024 + 16 * 4 * 64) * sizeof(float);
        fc_kernel<true, 4, 64><<<grid, 256, lds, stream>>>(hb1, fc2w, fc2b, hb2, 1024, 512, 512, 0);
    }
    matvec_kernel<<<256, 256, 0, stream>>>(hb2, outw, outb, out, 512);
}

// Round 17
// 724.162 us; speedup vs baseline: 1.1067x; 1.1067x over previous
//
#include <hip/hip_runtime.h>

// DGraphDTA r17 = r13 exact (best measured: 738.8us). r16's BK=32 falsified
// the barrier theory (VGPR 40->56, occ 56->40, conflicts 3x). Five GEMM
// restructures all lost to occupancy/VGPR/conflicts; 64x64/4x4/BK16 is the
// empirical optimum for this fp32 small-K GEMM.

static inline int cdiv(int a, int b) { return (a + b - 1) / b; }

// ---------------- fused CSR build ----------------

__global__ void deg2_kernel(const int* __restrict__ dstA, int* __restrict__ degA, int EA,
                            const int* __restrict__ dstB, int* __restrict__ degB, int EB) {
    int t = blockIdx.x * blockDim.x + threadIdx.x;
    if (t < EA) { atomicAdd(&degA[dstA[t]], 1); return; }
    t -= EA;
    if (t < EB) atomicAdd(&degB[dstB[t]], 1);
}

__global__ void degsum2_kernel(const int* __restrict__ deg_p, int NP, int nbp,
                               const int* __restrict__ deg_m, int NM, int* __restrict__ bsum) {
    __shared__ int s[256];
    int b = blockIdx.x, tid = threadIdx.x;
    const int* deg; int N, bi;
    if (b < nbp) { deg = deg_p; N = NP; bi = b; }
    else         { deg = deg_m; N = NM; bi = b - nbp; }
    int t = bi * 256 + tid;
    s[tid] = (t < N) ? deg[t] : 0;
    __syncthreads();
    for (int off = 128; off > 0; off >>= 1) {
        if (tid < off) s[tid] += s[tid + off];
        __syncthreads();
    }
    if (tid == 0) bsum[b] = s[0];
}

__global__ void scan2_kernel(int* __restrict__ bsum, int nbp, int nbm) {
    __shared__ int s[512];
    int tid = threadIdx.x;
    int total = nbp + nbm;
    int v = (tid < total) ? bsum[tid] : 0;
    bool isMol = (tid >= nbp);
    s[tid] = v;
    __syncthreads();
    for (int off = 1; off < 512; off <<= 1) {
        int x = 0;
        if (tid >= off) {
            int src = tid - off;
            if ((src >= nbp) == isMol) x = s[src];
        }
        __syncthreads();
        s[tid] += x;
        __syncthreads();
    }
    if (tid < total) bsum[tid] = s[tid] - v;
}

__global__ void alloc_scan2_kernel(const int* __restrict__ deg_p, int* rs_p, int* fc_p, float* n_p,
                                   int NP, int nbp,
                                   const int* __restrict__ deg_m, int* rs_m, int* fc_m, float* n_m,
                                   int NM, const int* __restrict__ bsum) {
    __shared__ int s[256];
    int b = blockIdx.x, tid = threadIdx.x;
    const int* deg; int* rs; int* fc; float* nrm; int N, bi;
    if (b < nbp) { deg = deg_p; rs = rs_p; fc = fc_p; nrm = n_p; N = NP; bi = b; }
    else         { deg = deg_m; rs = rs_m; fc = fc_m; nrm = n_m; N = NM; bi = b - nbp; }
    int t = bi * 256 + tid;
    int v = (t < N) ? deg[t] : 0;
    s[tid] = v;
    __syncthreads();
    for (int off = 1; off < 256; off <<= 1) {
        int x = (tid >= off) ? s[tid - off] : 0;
        __syncthreads();
        s[tid] += x;
        __syncthreads();
    }
    if (t < N) {
        int start = bsum[b] + s[tid] - v;
        rs[t] = start;
        fc[t] = start;
        nrm[t] = rsqrtf((float)v + 1.0f);
    }
}

__global__ void fill2_kernel(const int* srcA, const int* dstA, int* fcA, int* esA, int EA,
                             const int* srcB, const int* dstB, int* fcB, int* esB, int EB) {
    int t = blockIdx.x * blockDim.x + threadIdx.x;
    if (t < EA) { int p = atomicAdd(&fcA[dstA[t]], 1); esA[p] = srcA[t]; return; }
    t -= EA;
    if (t < EB) { int p = atomicAdd(&fcB[dstB[t]], 1); esB[p] = srcB[t]; }
}

__device__ __forceinline__ void gs_body(const int* batch, int* gs, int t, int N, int B) {
    int b = batch[t];
    int bp = (t == 0) ? -1 : batch[t - 1];
    for (int g = bp + 1; g <= b; ++g) gs[g] = t;
    if (t == N - 1) for (int g = b + 1; g <= B; ++g) gs[g] = N;
}

__global__ void gs2_kernel(const int* batchA, int* gsA, int NA,
                           const int* batchB, int* gsB, int NB, int B) {
    int t = blockIdx.x * blockDim.x + threadIdx.x;
    if (t < NA) { gs_body(batchA, gsA, t, NA, B); return; }
    t -= NA;
    if (t < NB) gs_body(batchB, gsB, t, NB, B);
}

__global__ void pad2_kernel(const float* xA, float* yA, int NA, int FA, int SA,
                            const float* xB, float* yB, int NB, int FB, int SB) {
    int t = blockIdx.x * blockDim.x + threadIdx.x;
    if (t < NA * SA) {
        int r = t / SA, j = t - r * SA;
        yA[t] = (j < FA) ? xA[(size_t)r * FA + j] : 0.0f;
        return;
    }
    t -= NA * SA;
    if (t < NB * SB) {
        int r = t / SB, j = t - r * SB;
        yB[t] = (j < FB) ? xB[(size_t)r * FB + j] : 0.0f;
    }
}

// ---------------- fused float4 gather-aggregate (norm fused) ----------------

__device__ __forceinline__ float4 vmad(float s, float4 a, float4 b) {
    return make_float4(fmaf(s, a.x, b.x), fmaf(s, a.y, b.y), fmaf(s, a.z, b.z), fmaf(s, a.w, b.w));
}
__device__ __forceinline__ float4 vmul(float s, float4 a) {
    return make_float4(s * a.x, s * a.y, s * a.z, s * a.w);
}

__device__ __forceinline__ void gather_body(
    const float* __restrict__ x, const float* __restrict__ norm,
    const int* __restrict__ row_start, const int* __restrict__ deg,
    const int* __restrict__ edge_src, float* __restrict__ agg, int t, int Fv)
{
    int n = t / Fv;
    int jv = t - n * Fv;
    const float4* xv = reinterpret_cast<const float4*>(x);
    float4* aggv = reinterpret_cast<float4*>(agg);

    float4 acc = vmul(norm[n], xv[(size_t)n * Fv + jv]);
    int rs = row_start[n];
    int d = deg[n];
    const int* es = edge_src + rs;
    int i = 0;
    for (; i + 2 <= d; i += 2) {
        int s0 = es[i], s1 = es[i + 1];
        float n0 = norm[s0], n1 = norm[s1];
        float4 v0 = xv[(size_t)s0 * Fv + jv];
        float4 v1 = xv[(size_t)s1 * Fv + jv];
        acc = vmad(n0, v0, acc);
        acc = vmad(n1, v1, acc);
    }
    if (i < d) {
        int s0 = es[i];
        acc = vmad(norm[s0], xv[(size_t)s0 * Fv + jv], acc);
    }
    aggv[t] = acc;
}

__global__ __launch_bounds__(256) void gather2_kernel(
    const float* xA, const float* nA, const int* rsA, const int* dA, const int* esA,
    float* aggA, int cntA, int FvA,
    const float* xB, const float* nB, const int* rsB, const int* dB, const int* esB,
    float* aggB, int cntB, int FvB)
{
    int t = blockIdx.x * blockDim.x + threadIdx.x;
    if (t < cntA) { gather_body(xA, nA, rsA, dA, esA, aggA, t, FvA); return; }
    t -= cntA;
    if (t < cntB) gather_body(xB, nB, rsB, dB, esB, aggB, t, FvB);
}

// ---------------- fused tiled GEMM (64x64/4x4, BK=16 — final) ----------------

__device__ __forceinline__ void gemm_body(
    const float* __restrict__ X, const float* __restrict__ W,
    const float* __restrict__ bias, const float* __restrict__ scale,
    float* __restrict__ out, int M, int K, int N, int lda, int out_stride,
    int bx, int by, float* As, float* Bs)
{
    constexpr int BM = 64, BN = 64, BK = 16, LDA = BM + 4;
    const int tid = threadIdx.x;
    const int row0 = by * BM, col0 = bx * BN;
    const int tx = tid & 15, ty = tid >> 4;

    float acc[4][4] = {};

    const int a_lr = tid >> 4;
    const int a_lk = tid & 15;
    const int b_lc = tid & 63;
    const int b_lk = tid >> 6;

    for (int k0 = 0; k0 < K; k0 += BK) {
#pragma unroll
        for (int p = 0; p < 4; ++p) {
            int r = a_lr + p * 16;
            int gm = row0 + r, gk = k0 + a_lk;
            As[a_lk * LDA + r] = (gm < M && gk < K) ? X[(size_t)gm * lda + gk] : 0.0f;
        }
#pragma unroll
        for (int p = 0; p < 4; ++p) {
            int kk = b_lk + p * 4;
            int gk = k0 + kk, gn = col0 + b_lc;
            Bs[kk * BN + b_lc] = (gk < K && gn < N) ? W[(size_t)gk * N + gn] : 0.0f;
        }
        __syncthreads();
#pragma unroll
        for (int k = 0; k < BK; ++k) {
            const float4 a4 = *reinterpret_cast<const float4*>(&As[k * LDA + ty * 4]);
            const float4 b4 = *reinterpret_cast<const float4*>(&Bs[k * BN + tx * 4]);
            const float av[4] = {a4.x, a4.y, a4.z, a4.w};
            const float bv[4] = {b4.x, b4.y, b4.z, b4.w};
#pragma unroll
            for (int i = 0; i < 4; ++i)
#pragma unroll
                for (int j = 0; j < 4; ++j)
                    acc[i][j] = fmaf(av[i], bv[j], acc[i][j]);
        }
        __syncthreads();
    }

#pragma unroll
    for (int i = 0; i < 4; ++i) {
        int gm = row0 + ty * 4 + i;
        if (gm >= M) continue;
        float sc = scale[gm];
#pragma unroll
        for (int j = 0; j < 4; ++j) {
            int gn = col0 + tx * 4 + j;
            if (gn >= N) continue;
            float v = sc * acc[i][j] + bias[gn];
            v = fmaxf(v, 0.0f);  // all node-layer gemms have relu
            out[(size_t)gm * out_stride + gn] = v;
        }
    }
}

__global__ __launch_bounds__(256) void gemm2_kernel(
    const float* XA, const float* WA, const float* biasA, const float* scaleA, float* outA,
    int MA, int KA, int NA, int ldaA, int osA, int nbA, int gxA,
    const float* XB, const float* WB, const float* biasB, const float* scaleB, float* outB,
    int MB, int KB, int NB, int ldaB, int osB, int gxB)
{
    __shared__ __align__(16) float As[16 * 68];
    __shared__ __align__(16) float Bs[16 * 64];
    int bid = blockIdx.x;
    if (bid < nbA) {
        gemm_body(XA, WA, biasA, scaleA, outA, MA, KA, NA, ldaA, osA, bid % gxA, bid / gxA, As, Bs);
    } else {
        bid -= nbA;
        gemm_body(XB, WB, biasB, scaleB, outB, MB, KB, NB, ldaB, osB, bid % gxB, bid / gxB, As, Bs);
    }
}

// ---------------- FC (M=256): M-reuse + deep split-K ----------------

template <bool RELU, int MR, int JT>
__device__ __forceinline__ void fc_body(
    const float* __restrict__ X, const float* __restrict__ W,
    const float* __restrict__ bias, float* __restrict__ out,
    int K, int N, int out_stride, int out_off, int bx, int by, float* smem)
{
    constexpr int TJ = JT / 4;
    constexpr int SK = 256 / TJ;
    float* Xs = smem;
    float* red = smem + MR * K;

    const int tid = threadIdx.x;
    const int m0 = by * MR;
    const int j0 = bx * JT;

    for (int idx = tid; idx < MR * K; idx += 256) {
        int r = idx / K, k = idx - r * K;
        Xs[idx] = X[(size_t)(m0 + r) * K + k];
    }
    __syncthreads();

    const int tj = tid % TJ;
    const int s  = tid / TJ;
    const int chunk = (K + SK - 1) / SK;
    const int kb = s * chunk;
    const int ke = min(K, kb + chunk);

    const float4* w4 = reinterpret_cast<const float4*>(W + j0) + tj;
    const int wstride = N >> 2;

    float4 acc[MR];
#pragma unroll
    for (int r = 0; r < MR; ++r) acc[r] = make_float4(0.f, 0.f, 0.f, 0.f);
    for (int k = kb; k < ke; ++k) {
        float4 w = w4[(size_t)k * wstride];
#pragma unroll
        for (int r = 0; r < MR; ++r)
            acc[r] = vmad(Xs[r * K + k], w, acc[r]);
    }
#pragma unroll
    for (int r = 0; r < MR; ++r) {
        float* rr = red + ((s * MR + r) * JT) + tj * 4;
        rr[0] = acc[r].x; rr[1] = acc[r].y; rr[2] = acc[r].z; rr[3] = acc[r].w;
    }
    __syncthreads();

    for (int o = tid; o < MR * JT; o += 256) {
        int r = o / JT, j = o - r * JT;
        float v = 0.f;
#pragma unroll
        for (int ss = 0; ss < SK; ++ss) v += red[(ss * MR + r) * JT + j];
        v += bias[j0 + j];
        if (RELU) v = fmaxf(v, 0.0f);
        out[(size_t)(m0 + r) * out_stride + out_off + j0 + j] = v;
    }
}

template <bool RELU, int MR, int JT>
__global__ __launch_bounds__(256) void fc2_kernel(
    const float* XA, const float* WA, const float* bA, float* oA,
    int KA, int NA, int osA, int ooA, int nbA, int gxA,
    const float* XB, const float* WB, const float* bB, float* oB,
    int KB, int NB, int osB, int ooB, int gxB)
{
    extern __shared__ float smem[];
    int bid = blockIdx.x;
    if (bid < nbA) {
        fc_body<RELU, MR, JT>(XA, WA, bA, oA, KA, NA, osA, ooA, bid % gxA, bid / gxA, smem);
    } else {
        bid -= nbA;
        fc_body<RELU, MR, JT>(XB, WB, bB, oB, KB, NB, osB, ooB, bid % gxB, bid / gxB, smem);
    }
}

template <bool RELU, int MR, int JT>
__global__ __launch_bounds__(256) void fc_kernel(
    const float* X, const float* W, const float* b, float* o,
    int K, int N, int out_stride, int out_off)
{
    extern __shared__ float smem[];
    fc_body<RELU, MR, JT>(X, W, b, o, K, N, out_stride, out_off, blockIdx.x, blockIdx.y, smem);
}

// final layer: one block per row, 256 threads, LDS tree reduce (K=512)
__global__ __launch_bounds__(256) void matvec_kernel(
    const float* __restrict__ X, const float* __restrict__ W,
    const float* __restrict__ bias, float* __restrict__ out, int K)
{
    __shared__ float red[256];
    const int m = blockIdx.x;
    const int tid = threadIdx.x;
    float acc = 0.f;
    for (int k = tid; k < K; k += 256) acc = fmaf(X[(size_t)m * K + k], W[k], acc);
    red[tid] = acc;
    __syncthreads();
    for (int w = 128; w >= 64; w >>= 1) {
        if (tid < w) red[tid] += red[tid + w];
        __syncthreads();
    }
    if (tid < 64) {
        float v = red[tid];
        for (int off = 32; off > 0; off >>= 1) v += __shfl_down(v, off, 64);
        if (tid == 0) out[m] = v + bias[0];
    }
}

// ---------------- fused pooling ----------------

__device__ __forceinline__ void pool_body(const float* __restrict__ x, const int* __restrict__ gs,
                                          float* __restrict__ pool, int t, int F, int stride) {
    int g = t / F;
    int j = t - g * F;
    int s = gs[g];
    int c = gs[g + 1] - s;
    float acc = 0.0f;
    for (int i = 0; i < c; ++i) acc += x[(size_t)(s + i) * stride + j];
    pool[t] = acc / (float)max(c, 1);
}

__global__ void pool2_kernel(const float* xA, const int* gsA, float* poolA, int cntA, int FA, int strA,
                             const float* xB, const int* gsB, float* poolB, int cntB, int FB, int strB) {
    int t = blockIdx.x * blockDim.x + threadIdx.x;
    if (t < cntA) { pool_body(xA, gsA, poolA, t, FA, strA); return; }
    t -= cntA;
    if (t < cntB) pool_body(xB, gsB, poolB, t, FB, strB);
}

extern "C" void kernel_launch(void* const* d_in, const int* in_sizes, int n_in,
                              void* d_out, int out_size, void* d_ws, size_t ws_size,
                              hipStream_t stream) {
    const float* mol_x     = (const float*)d_in[0];
    const int*   mol_ei    = (const int*)  d_in[1];
    const int*   mol_batch = (const int*)  d_in[2];
    const float* pro_x     = (const float*)d_in[3];
    const int*   pro_ei    = (const int*)  d_in[4];
    const int*   pro_batch = (const int*)  d_in[5];
    const float* mw1 = (const float*)d_in[6],  * mb1 = (const float*)d_in[7];
    const float* mw2 = (const float*)d_in[8],  * mb2 = (const float*)d_in[9];
    const float* mw3 = (const float*)d_in[10], * mb3 = (const float*)d_in[11];
    const float* mfw1 = (const float*)d_in[12], * mfb1 = (const float*)d_in[13];
    const float* mfw2 = (const float*)d_in[14], * mfb2 = (const float*)d_in[15];
    const float* pw1 = (const float*)d_in[16], * pb1 = (const float*)d_in[17];
    const float* pw2 = (const float*)d_in[18], * pb2 = (const float*)d_in[19];
    const float* pw3 = (const float*)d_in[20], * pb3 = (const float*)d_in[21];
    const float* pfw1 = (const float*)d_in[22], * pfb1 = (const float*)d_in[23];
    const float* pfw2 = (const float*)d_in[24], * pfb2 = (const float*)d_in[25];
    const float* fc1w = (const float*)d_in[26], * fc1b = (const float*)d_in[27];
    const float* fc2w = (const float*)d_in[28], * fc2b = (const float*)d_in[29];
    const float* outw = (const float*)d_in[30], * outb = (const float*)d_in[31];
    float* out = (float*)d_out;

    // ---- dims ----
    const int NP = 76800, EP = 768000;
    const int NM = 10240, EM = 40960;
    const int NBP = cdiv(NP, 256), NBM = cdiv(NM, 256);  // 300, 40

    // ---- workspace layout (floats then ints), ~167 MB ----
    float* Pp = (float*)d_ws;                  // 76800*216
    float* Qp = Pp + (size_t)NP * 216;         // 76800*108
    float* Rp = Qp + (size_t)NP * 108;         // 76800*108
    float* Pm = Rp + (size_t)NP * 108;         // 10240*312
    float* Qm = Pm + (size_t)NM * 312;         // 10240*156
    float* Rm = Qm + (size_t)NM * 156;         // 10240*156
    float* norm_p = Rm + (size_t)NM * 156;     // 76800
    float* norm_m = norm_p + NP;               // 10240
    float* pool_p = norm_m + NM;               // 256*216
    float* pool_m = pool_p + 256 * 216;        // 256*312
    float* fcb_p  = pool_m + 256 * 312;        // 256*1024
    float* fcb_m  = fcb_p + 256 * 1024;        // 256*1024
    float* xc     = fcb_m + 256 * 1024;        // 256*256
    float* hb1    = xc + 256 * 256;            // 256*1024
    float* hb2    = hb1 + 256 * 1024;          // 256*512
    int* ibase    = (int*)(hb2 + 256 * 512);
    int* deg_p = ibase;                        // 76800 (memset region start)
    int* deg_m = deg_p + NP;                   // 10240
    int* rs_p  = deg_m + NM;                   // 76800
    int* fc_p  = rs_p + NP;                    // 76800
    int* es_p  = fc_p + NP;                    // 768000
    int* rs_m  = es_p + EP;                    // 10240
    int* fc_m  = rs_m + NM;                    // 10240
    int* es_m  = fc_m + NM;                    // 40960
    int* gs_p  = es_m + EM;                    // 257 (+pad)
    int* gs_m  = gs_p + 260;                   // 257 (+pad)
    int* bsum  = gs_m + 260;                   // 384 (NBP+NBM=340)

    const int BLK = 256;

    // ---- fused CSR build (atomic-free allocation via block scans) ----
    hipMemsetAsync(deg_p, 0, (size_t)(NP + NM) * sizeof(int), stream);
    deg2_kernel<<<cdiv(EP + EM, BLK), BLK, 0, stream>>>(pro_ei + EP, deg_p, EP, mol_ei + EM, deg_m, EM);
    degsum2_kernel<<<NBP + NBM, 256, 0, stream>>>(deg_p, NP, NBP, deg_m, NM, bsum);
    scan2_kernel<<<1, 512, 0, stream>>>(bsum, NBP, NBM);
    alloc_scan2_kernel<<<NBP + NBM, 256, 0, stream>>>(deg_p, rs_p, fc_p, norm_p, NP, NBP,
                                                      deg_m, rs_m, fc_m, norm_m, NM, bsum);
    fill2_kernel<<<cdiv(EP + EM, BLK), BLK, 0, stream>>>(pro_ei, pro_ei + EP, fc_p, es_p, EP,
                                                         mol_ei, mol_ei + EM, fc_m, es_m, EM);
    gs2_kernel<<<cdiv(NP + NM, BLK), BLK, 0, stream>>>(pro_batch, gs_p, NP, mol_batch, gs_m, NM, 256);
    pad2_kernel<<<cdiv(NP * 56 + NM * 80, BLK), BLK, 0, stream>>>(pro_x, Rp, NP, 54, 56,
                                                                  mol_x, Rm, NM, 78, 80);

    // fused layer: gather both branches, then gemm both branches
    auto layer = [&](const float* xp, float* outp, const float* Wp, const float* bp,
                     int KpF, int Sp, int NpF, int SpO,
                     const float* xm, float* outm, const float* Wm, const float* bm,
                     int KmF, int Sm, int NmF, int SmO) {
        int cntP = NP * (Sp / 4), cntM = NM * (Sm / 4);
        gather2_kernel<<<cdiv(cntP + cntM, BLK), BLK, 0, stream>>>(
            xp, norm_p, rs_p, deg_p, es_p, Qp, cntP, Sp / 4,
            xm, norm_m, rs_m, deg_m, es_m, Qm, cntM, Sm / 4);
        int gxA = cdiv(NpF, 64), gyA = cdiv(NP, 64), nbA = gxA * gyA;
        int gxB = cdiv(NmF, 64), gyB = cdiv(NM, 64), nbB = gxB * gyB;
        gemm2_kernel<<<nbA + nbB, 256, 0, stream>>>(
            Qp, Wp, bp, norm_p, outp, NP, KpF, NpF, Sp, SpO, nbA, gxA,
            Qm, Wm, bm, norm_m, outm, NM, KmF, NmF, Sm, SmO, gxB);
    };

    // L1: R(padded x0) -> P ; L2: P -> R ; L3: R -> P
    layer(Rp, Pp, pw1, pb1, 54, 56, 54, 56,   Rm, Pm, mw1, mb1, 78, 80, 78, 80);
    layer(Pp, Rp, pw2, pb2, 54, 56, 108, 108, Pm, Rm, mw2, mb2, 78, 80, 156, 156);
    layer(Rp, Pp, pw3, pb3, 108, 108, 216, 216, Rm, Pm, mw3, mb3, 156, 156, 312, 312);

    // fused pool
    pool2_kernel<<<cdiv(256 * 216 + 256 * 312, BLK), BLK, 0, stream>>>(
        Pp, gs_p, pool_p, 256 * 216, 216, 216,
        Pm, gs_m, pool_m, 256 * 312, 312, 312);

    // fused branch fc1 (relu, K=216/312, N=1024): MR=4, JT=64; LDS sized for K=312
    {
        int gxA = 1024 / 64, nbA = gxA * (256 / 4);
        int gxB = 1024 / 64, nbB = gxB * (256 / 4);
        size_t lds = (size_t)(4 * 312 + 16 * 4 * 64) * sizeof(float);
        fc2_kernel<true, 4, 64><<<nbA + nbB, 256, lds, stream>>>(
            pool_p, pfw1, pfb1, fcb_p, 216, 1024, 1024, 0, nbA, gxA,
            pool_m, mfw1, mfb1, fcb_m, 312, 1024, 1024, 0, gxB);
    }
    // fused branch fc2 (no relu, K=1024, N=128 -> xc cols): MR=2, JT=32
    {
        int gxA = 128 / 32, nbA = gxA * (256 / 2);
        int gxB = gxA, nbB = nbA;
        size_t lds = (size_t)(2 * 1024 + 32 * 2 * 32) * sizeof(float);
        fc2_kernel<false, 2, 32><<<nbA + nbB, 256, lds, stream>>>(
            fcb_p, pfw2, pfb2, xc, 1024, 128, 256, 128, nbA, gxA,
            fcb_m, mfw2, mfb2, xc, 1024, 128, 256, 0, gxB);
    }

    // combined head
    {
        dim3 grid(1024 / 64, 256 / 4);
        size_t lds = (size_t)(4 * 256 + 16 * 4 * 64) * sizeof(float);
        fc_kernel<true, 4, 64><<<grid, 256, lds, stream>>>(xc, fc1w, fc1b, hb1, 256, 1024, 1024, 0);
    }
    {
        dim3 grid(512 / 64, 256 / 4);
        size_t lds = (size_t)(4 * 1024 + 16 * 4 * 64) * sizeof(float);
        fc_kernel<true, 4, 64><<<grid, 256, lds, stream>>>(hb1, fc2w, fc2b, hb2, 1024, 512, 512, 0);
    }
    matvec_kernel<<<256, 256, 0, stream>>>(hb2, outw, outb, out, 512);
}